// Round 13
// baseline (483.397 us; speedup 1.0000x reference)
//
#include <hip/hip_runtime.h>

// Problem constants (from reference)
#define B_TREES 32
#define DEPTH   12
#define M_NODES 4095                  // 2^12 - 1
#define N_NODES (B_TREES * M_NODES)   // 131040
#define HDIM    256
#define VOCAB   32000
#define NCLS    20
#define LEAFROWS 65536                // 32 * 2048 leaves
#define LDSH_S 20                     // padded stride of 16x16 h transpose tile

typedef _Float16 f16;
typedef _Float16 f16x8 __attribute__((ext_vector_type(8)));
typedef _Float16 f16x4 __attribute__((ext_vector_type(4)));
typedef _Float16 f16x2 __attribute__((ext_vector_type(2)));
typedef float    f32x4 __attribute__((ext_vector_type(4)));

__device__ __forceinline__ float sigf(float x)      { return 1.0f / (1.0f + __expf(-x)); }
__device__ __forceinline__ float tanh_fast(float x) { return 1.0f - 2.0f / (1.0f + __expf(2.0f * x)); }

// ---------------------------------------------------------------------------
// Init: convert Emb + weights to fp16. W_out padded to 32 rows (zeros).
// ---------------------------------------------------------------------------
__global__ __launch_bounds__(256) void cvt_kernel(
    const float4* __restrict__ Emb,  const float4* __restrict__ Wiou,
    const float4* __restrict__ Uiou, const float4* __restrict__ Uf,
    const float4* __restrict__ Wout,
    f16x4* __restrict__ Emb16,  f16x4* __restrict__ Wiou16,
    f16x4* __restrict__ Uiou16, f16x4* __restrict__ Uf16,
    f16x4* __restrict__ Wout16)
{
    int i = blockIdx.x * 256 + threadIdx.x;   // in units of 4 floats
    if (i < VOCAB * HDIM / 4) {
        float4 v = Emb[i];
        f16x4 r; r[0] = (f16)v.x; r[1] = (f16)v.y; r[2] = (f16)v.z; r[3] = (f16)v.w;
        Emb16[i] = r;
    }
    if (i < 768 * HDIM / 4) {
        float4 v = Wiou[i];
        f16x4 r; r[0] = (f16)v.x; r[1] = (f16)v.y; r[2] = (f16)v.z; r[3] = (f16)v.w;
        Wiou16[i] = r;
        float4 u = Uiou[i];
        f16x4 s; s[0] = (f16)u.x; s[1] = (f16)u.y; s[2] = (f16)u.z; s[3] = (f16)u.w;
        Uiou16[i] = s;
    }
    if (i < HDIM * HDIM / 4) {
        float4 v = Uf[i];
        f16x4 r; r[0] = (f16)v.x; r[1] = (f16)v.y; r[2] = (f16)v.z; r[3] = (f16)v.w;
        Uf16[i] = r;
    }
    if (i < 32 * HDIM / 4) {                  // 32 padded rows of W_out
        int row = i >> 6;
        f16x4 r = {};
        if (row < NCLS) {
            float4 v = Wout[i];
            r[0] = (f16)v.x; r[1] = (f16)v.y; r[2] = (f16)v.z; r[3] = (f16)v.w;
        }
        Wout16[i] = r;
    }
}

// ---------------------------------------------------------------------------
// Vocab kernel: leaf h,c are pure functions of token id (h_sum = fc_sum = 0),
// so compute them ONCE per vocab entry: hv[id][256], cv[id][256] (f16).
// Sequential-row GEMM (32000 rows, no gather). 1D grid, XCD-aware: blocks
// round-robin across 8 XCD L2s by id%8; each XCD owns a contiguous stripe
// range with all 16 col-groups. Grid 1664 = 8 xcd * 13 sl * 16 cg.
// ---------------------------------------------------------------------------
#define VTPW 5
__global__ __launch_bounds__(256) void vocab_kernel(
    const f16* __restrict__ Emb16, const f16* __restrict__ Wiou16,
    const float* __restrict__ b_iou,
    f16* __restrict__ hv, f16* __restrict__ cv)
{
    __shared__ f16 wlds[1536 * 8];             // 24 KB: [mat][ks][quad][col] 16B frags
    __shared__ f16 ldshH[4][16 * LDSH_S];
    __shared__ f16 ldshC[4][16 * LDSH_S];

    const int id     = blockIdx.x;
    const int xcd    = id & 7;
    const int slot   = id >> 3;
    const int cg     = slot & 15;
    const int stripe = xcd * 13 + (slot >> 4);
    if (stripe >= 100) return;                 // padded tail (uniform per block)

    const int tid  = threadIdx.x;
    const int lane = tid & 63;
    const int w    = tid >> 6;
    const int quad = lane >> 4;
    const int l15  = lane & 15;
    const int qk   = quad * 8;
    const int cb0  = cg * 16;                  // block's 16 cols

    // Stage weights (frag f = mat*512 + ks*64 + quad*16 + col)
    #pragma unroll
    for (int i = 0; i < 6; ++i) {
        int f = i * 256 + tid;
        int mat = f >> 9, r = f & 511, ks = r >> 6, q = (r >> 4) & 3, c = r & 15;
        *(f16x8*)(wlds + f * 8) = *(const f16x8*)(Wiou16 +
            (mat * 256 + cb0 + c) * HDIM + ks * 32 + q * 8);
    }
    __syncthreads();

    const float bi = b_iou[cb0 + l15];
    const float bo = b_iou[256 + cb0 + l15];
    const float bu = b_iou[512 + cb0 + l15];

    const int row0 = (stripe * 4 + w) * (VTPW * 16);  // wave's 80 rows

    // Prefetch tile 0 (sequential rows, no indirection)
    f16x8 a[8];
    #pragma unroll
    for (int ks = 0; ks < 8; ++ks)
        a[ks] = *(const f16x8*)(Emb16 + (row0 + l15) * HDIM + ks * 32 + qk);

    for (int rt = 0; rt < VTPW; ++rt) {
        const int rw = row0 + rt * 16;
        f16x8 ac[8];
        #pragma unroll
        for (int ks = 0; ks < 8; ++ks) ac[ks] = a[ks];

        if (rt + 1 < VTPW) {                   // prefetch next tile
            #pragma unroll
            for (int ks = 0; ks < 8; ++ks)
                a[ks] = *(const f16x8*)(Emb16 + (rw + 16 + l15) * HDIM + ks * 32 + qk);
        }

        f32x4 acc[3] = {};
        #pragma unroll
        for (int ks = 0; ks < 8; ++ks) {
            #pragma unroll
            for (int mat = 0; mat < 3; ++mat) {
                f16x8 wf = *(const f16x8*)(wlds +
                    ((mat * 8 + ks) * 64 + quad * 16 + l15) * 8);
                acc[mat] = __builtin_amdgcn_mfma_f32_16x16x32_f16(
                    ac[ks], wf, acc[mat], 0, 0, 0);
            }
        }

        // Epilogue: activations, transpose both h and c tiles via LDS
        #pragma unroll
        for (int r = 0; r < 4; ++r) {
            float i_ = acc[0][r] + bi;
            float o_ = acc[1][r] + bo;
            float u_ = acc[2][r] + bu;
            float c  = sigf(i_) * tanh_fast(u_);
            float h  = sigf(o_) * tanh_fast(c);
            ldshH[w][(quad * 4 + r) * LDSH_S + l15] = (f16)h;
            ldshC[w][(quad * 4 + r) * LDSH_S + l15] = (f16)c;
        }

        // Wave-local drain (row-major hv / cv, 8B stores)
        {
            int row_l = lane >> 2, cpos = (lane & 3) * 4;
            f16x4 vh = *(const f16x4*)(&ldshH[w][row_l * LDSH_S + cpos]);
            *(f16x4*)(hv + (rw + row_l) * HDIM + cb0 + cpos) = vh;
            f16x4 vc = *(const f16x4*)(&ldshC[w][row_l * LDSH_S + cpos]);
            *(f16x4*)(cv + (rw + row_l) * HDIM + cb0 + cpos) = vc;
        }
    }
}

// ---------------------------------------------------------------------------
// Vocab output head: out_v[id] = hv[id] @ W_out^T + b_out (fp32, 20 cols).
// ---------------------------------------------------------------------------
__global__ __launch_bounds__(256) void vocab_out_kernel(
    const f16* __restrict__ hv, const f16* __restrict__ Wout16,
    const float* __restrict__ bout, float* __restrict__ out_v)
{
    const int lane = threadIdx.x & 63;
    const int w    = threadIdx.x >> 6;
    const int quad = lane >> 4;
    const int l15  = lane & 15;
    const int qk   = quad * 8;

    f16x8 wfk[2][8];
    #pragma unroll
    for (int cf = 0; cf < 2; ++cf)
        #pragma unroll
        for (int ks = 0; ks < 8; ++ks)
            wfk[cf][ks] = *(const f16x8*)(Wout16 +
                (cf * 16 + l15) * HDIM + ks * 32 + qk);
    float bo[2];
    #pragma unroll
    for (int cf = 0; cf < 2; ++cf) {
        int col = cf * 16 + l15;
        bo[cf] = bout[col < NCLS ? col : 0];
    }

    const int tile0 = blockIdx.x * 16;         // 2000 tiles total, grid 125

    for (int rt = w; rt < 16; rt += 4) {
        const int rw = (tile0 + rt) * 16;
        f32x4 acc[2] = {};
        #pragma unroll
        for (int ks = 0; ks < 8; ++ks) {
            f16x8 a = *(const f16x8*)(hv + (rw + l15) * HDIM + ks * 32 + qk);
            #pragma unroll
            for (int cf = 0; cf < 2; ++cf)
                acc[cf] = __builtin_amdgcn_mfma_f32_16x16x32_f16(
                    a, wfk[cf][ks], acc[cf], 0, 0, 0);
        }
        #pragma unroll
        for (int cf = 0; cf < 2; ++cf) {
            const int col = cf * 16 + l15;
            if (col < NCLS) {
                #pragma unroll
                for (int r = 0; r < 4; ++r)
                    out_v[(rw + quad * 4 + r) * NCLS + col] = acc[cf][r] + bo[cf];
            }
        }
    }
}

// ---------------------------------------------------------------------------
// Leaf scatter: per leaf row, gather hv[id] -> h16[node] (coalesced copy),
// cv[id] -> LDS -> transposed cT[col][row], out_v[id] -> out[node] rows.
// 64 leaves per block, grid 1024.
// ---------------------------------------------------------------------------
__global__ __launch_bounds__(256) void leaf_scatter_kernel(
    const int* __restrict__ x, const f16* __restrict__ hv,
    const f16* __restrict__ cv, const float* __restrict__ out_v,
    f16* __restrict__ h16, f16* __restrict__ cT, float* __restrict__ out)
{
    __shared__ int ids[64];
    __shared__ f16 ldsc[64][HDIM + 8];         // +16B pad: 2-way (free) col reads

    const int tid = threadIdx.x;
    const int R0  = blockIdx.x * 64;           // block's 64 leaf rows

    if (tid < 64) {
        int r = R0 + tid;
        int node = (r >> 11) * M_NODES + 2047 + (r & 2047);
        ids[tid] = x[node];
    }
    __syncthreads();

    const int r    = tid >> 2;                 // 0..63
    const int p    = tid & 3;                  // 0..3  (128 B segment)
    const int id   = ids[r];
    const int gr   = R0 + r;
    const int node = (gr >> 11) * M_NODES + 2047 + (gr & 2047);

    // h: gather row -> coalesced row-major write
    #pragma unroll
    for (int j = 0; j < 8; ++j) {
        f16x8 v = *(const f16x8*)(hv + id * HDIM + p * 64 + j * 8);
        *(f16x8*)(h16 + node * HDIM + p * 64 + j * 8) = v;
    }
    // c: gather row -> LDS (row-major stage)
    #pragma unroll
    for (int j = 0; j < 8; ++j) {
        f16x8 v = *(const f16x8*)(cv + id * HDIM + p * 64 + j * 8);
        *(f16x8*)(&ldsc[r][p * 64 + j * 8]) = v;
    }
    // out head: 20 floats per leaf, 5 per thread
    #pragma unroll
    for (int j = 0; j < 5; ++j)
        out[node * NCLS + p * 5 + j] = out_v[id * NCLS + p * 5 + j];

    __syncthreads();

    // transpose drain: thread owns col tid, writes 128 B contiguous per col
    {
        const int c = tid;
        f16 tmp[64];
        #pragma unroll
        for (int rr = 0; rr < 64; ++rr) tmp[rr] = ldsc[rr][c];
        #pragma unroll
        for (int j = 0; j < 8; ++j)
            *(f16x8*)(cT + c * LEAFROWS + R0 + j * 8) = *(const f16x8*)(&tmp[j * 8]);
    }
}

// ---------------------------------------------------------------------------
// BIG levels (l>=8): R8-exact persistent stripe loop (measured 85.3 us @l=10).
// Grid 512 = 8 xcd * 16 cg * 4 slots; XCD-bijective stripe chunks.
// ---------------------------------------------------------------------------
__global__ __launch_bounds__(512) void fused_level_looped(
    const f16* __restrict__ Uiou16, const f16* __restrict__ Uf16,
    const float* __restrict__ b_iou, const float* __restrict__ b_f,
    f16* __restrict__ h16, const f16* __restrict__ cT_child,
    f16* __restrict__ cT_parent, int l, int rows_p, int nstripes)
{
    __shared__ f16 wlds[2048 * 8];             // 32 KB: mat0=Uf, mat1..3=Uiou
    __shared__ f16 ldsh[8][16 * LDSH_S];

    const int id   = blockIdx.x;
    const int cg   = (id >> 3) & 15;
    const int spx  = nstripes >> 3;            // stripes per xcd (nstripes%8==0)
    const int sbase  = (id & 7) * spx;
    const int sfirst = id >> 7;                // slot 0..3
    const int scount = spx;

    const int tid  = threadIdx.x;
    const int lane = tid & 63;
    const int w    = tid >> 6;                 // 0..7
    const int quad = lane >> 4;
    const int l15  = lane & 15;
    const int qk   = quad * 8;
    const int cb0  = cg * 16;

    // Stage weights once per block (2048 frags, 512 threads -> 4 iters)
    #pragma unroll
    for (int i = 0; i < 4; ++i) {
        int f = i * 512 + tid;
        int mat = f >> 9, r = f & 511, ks = r >> 6, q = (r >> 4) & 3, c = r & 15;
        const f16* src = (mat == 0)
            ? (Uf16 + (cb0 + c) * HDIM + ks * 32 + q * 8)
            : (Uiou16 + ((mat - 1) * 256 + cb0 + c) * HDIM + ks * 32 + q * 8);
        *(f16x8*)(wlds + f * 8) = *(const f16x8*)src;
    }
    __syncthreads();

    const float bi  = b_iou[cb0 + l15];
    const float bo  = b_iou[256 + cb0 + l15];
    const float bu  = b_iou[512 + cb0 + l15];
    const float bfv = b_f[cb0 + l15];
    const int lc = l + 1;
    const int maskc = (1 << lc) - 1;
    const int maskp = (1 << l) - 1;
    const int rows_c = rows_p * 2;

    for (int s = sfirst; s < scount; s += 4) {
        const int stripe = sbase + s;
        const int pw = stripe * 128 + w * 16;  // wave's 16-parent tile
        const int cw = 2 * pw;

        int childBase0, childBase1;
        {
            int cl0 = cw + l15;
            childBase0 = ((cl0 >> lc) * M_NODES + maskc + (cl0 & maskc)) * HDIM;
            int cl1 = cw + 16 + l15;
            childBase1 = ((cl1 >> lc) * M_NODES + maskc + (cl1 & maskc)) * HDIM;
        }

        f32x4 accf0 = {}, accf1 = {};
        f32x4 au0[3] = {}, au1[3] = {};
        #pragma unroll
        for (int ks = 0; ks < 8; ++ks) {
            const int k0 = ks * 32 + qk;
            f16x8 a0 = *(const f16x8*)(h16 + childBase0 + k0);
            f16x8 a1 = *(const f16x8*)(h16 + childBase1 + k0);
            f16x8 wfF = *(const f16x8*)(wlds + (ks * 64 + quad * 16 + l15) * 8);
            accf0 = __builtin_amdgcn_mfma_f32_16x16x32_f16(a0, wfF, accf0, 0, 0, 0);
            accf1 = __builtin_amdgcn_mfma_f32_16x16x32_f16(a1, wfF, accf1, 0, 0, 0);
            #pragma unroll
            for (int m = 0; m < 3; ++m) {
                f16x8 wm = *(const f16x8*)(wlds +
                    (((m + 1) * 8 + ks) * 64 + quad * 16 + l15) * 8);
                au0[m] = __builtin_amdgcn_mfma_f32_16x16x32_f16(a0, wm, au0[m], 0, 0, 0);
                au1[m] = __builtin_amdgcn_mfma_f32_16x16x32_f16(a1, wm, au1[m], 0, 0, 0);
            }
        }

        // Epilogue: two child sets -> parents pw..pw+7 and pw+8..pw+15
        #pragma unroll
        for (int sh = 0; sh < 2; ++sh) {
            const f32x4& af = sh ? accf1 : accf0;
            const f32x4* au = sh ? au1 : au0;
            const int csr = cw + sh * 16;         // child rows of this set
            f16x4 cc = *(const f16x4*)(cT_child +
                (cb0 + l15) * rows_c + csr + quad * 4);
            f16x2 cpack;
            #pragma unroll
            for (int pr = 0; pr < 2; ++pr) {
                float f0 = sigf(af[2 * pr]     + bfv);
                float f1 = sigf(af[2 * pr + 1] + bfv);
                float fc = f0 * (float)cc[2 * pr] + f1 * (float)cc[2 * pr + 1];
                float i_ = au[0][2 * pr] + au[0][2 * pr + 1] + bi;
                float o_ = au[1][2 * pr] + au[1][2 * pr + 1] + bo;
                float u_ = au[2][2 * pr] + au[2][2 * pr + 1] + bu;
                float c  = sigf(i_) * tanh_fast(u_) + fc;
                float h  = sigf(o_) * tanh_fast(c);
                cpack[pr] = (f16)c;
                ldsh[w][(sh * 8 + quad * 2 + pr) * LDSH_S + l15] = (f16)h;
            }
            *(f16x2*)(cT_parent + (cb0 + l15) * rows_p + pw + sh * 8 + quad * 2) = cpack;
        }

        // Wave-local drain of 16-parent x 16-col h tile (8B stores)
        {
            int prow = lane >> 2, cpos = (lane & 3) * 4;
            int p = pw + prow;
            int b = p >> l, tt = p & maskp;
            int node = b * M_NODES + (1 << l) - 1 + tt;
            f16x4 v = *(const f16x4*)(&ldsh[w][prow * LDSH_S + cpos]);
            *(f16x4*)(h16 + node * HDIM + cb0 + cpos) = v;
        }
    }
}

// ---------------------------------------------------------------------------
// MID levels (l=7,6,5): R8-proven plain kernel. Grid nstripes*16, one
// 16-parent tile per wave.
// ---------------------------------------------------------------------------
__global__ __launch_bounds__(512) void fused_level_small(
    const f16* __restrict__ Uiou16, const f16* __restrict__ Uf16,
    const float* __restrict__ b_iou, const float* __restrict__ b_f,
    f16* __restrict__ h16, const f16* __restrict__ cT_child,
    f16* __restrict__ cT_parent, int l, int rows_p)
{
    __shared__ f16 wlds[2048 * 8];             // 32 KB: mat0=Uf, mat1..3=Uiou
    __shared__ f16 ldsh[8][16 * LDSH_S];

    const int id = blockIdx.x;
    const int cg    = id & 15;
    const int sbase = id >> 4;

    const int tid  = threadIdx.x;
    const int lane = tid & 63;
    const int w    = tid >> 6;                 // 0..7
    const int quad = lane >> 4;
    const int l15  = lane & 15;
    const int qk   = quad * 8;
    const int cb0  = cg * 16;

    // Stage weights (2048 frags, 512 threads -> 4 iters)
    #pragma unroll
    for (int i = 0; i < 4; ++i) {
        int f = i * 512 + tid;
        int mat = f >> 9, r = f & 511, ks = r >> 6, q = (r >> 4) & 3, c = r & 15;
        const f16* src = (mat == 0)
            ? (Uf16 + (cb0 + c) * HDIM + ks * 32 + q * 8)
            : (Uiou16 + ((mat - 1) * 256 + cb0 + c) * HDIM + ks * 32 + q * 8);
        *(f16x8*)(wlds + f * 8) = *(const f16x8*)src;
    }
    __syncthreads();

    const float bi  = b_iou[cb0 + l15];
    const float bo  = b_iou[256 + cb0 + l15];
    const float bu  = b_iou[512 + cb0 + l15];
    const float bfv = b_f[cb0 + l15];
    const int lc = l + 1;
    const int maskc = (1 << lc) - 1;
    const int maskp = (1 << l) - 1;
    const int rows_c = rows_p * 2;

    const int pw = sbase * 128 + w * 16;       // wave's 16-parent tile
    if (pw >= rows_p) return;
    const int cw = 2 * pw;

    int childBase0, childBase1;
    {
        int cl0 = cw + l15;
        childBase0 = ((cl0 >> lc) * M_NODES + maskc + (cl0 & maskc)) * HDIM;
        int cl1 = cw + 16 + l15;
        childBase1 = ((cl1 >> lc) * M_NODES + maskc + (cl1 & maskc)) * HDIM;
    }

    f32x4 accf0 = {}, accf1 = {};
    f32x4 au0[3] = {}, au1[3] = {};
    #pragma unroll
    for (int ks = 0; ks < 8; ++ks) {
        const int k0 = ks * 32 + qk;
        f16x8 a0 = *(const f16x8*)(h16 + childBase0 + k0);
        f16x8 a1 = *(const f16x8*)(h16 + childBase1 + k0);
        f16x8 wfF = *(const f16x8*)(wlds + (ks * 64 + quad * 16 + l15) * 8);
        accf0 = __builtin_amdgcn_mfma_f32_16x16x32_f16(a0, wfF, accf0, 0, 0, 0);
        accf1 = __builtin_amdgcn_mfma_f32_16x16x32_f16(a1, wfF, accf1, 0, 0, 0);
        #pragma unroll
        for (int m = 0; m < 3; ++m) {
            f16x8 wm = *(const f16x8*)(wlds +
                (((m + 1) * 8 + ks) * 64 + quad * 16 + l15) * 8);
            au0[m] = __builtin_amdgcn_mfma_f32_16x16x32_f16(a0, wm, au0[m], 0, 0, 0);
            au1[m] = __builtin_amdgcn_mfma_f32_16x16x32_f16(a1, wm, au1[m], 0, 0, 0);
        }
    }

    #pragma unroll
    for (int sh = 0; sh < 2; ++sh) {
        const f32x4& af = sh ? accf1 : accf0;
        const f32x4* au = sh ? au1 : au0;
        const int csr = cw + sh * 16;
        f16x4 cc = *(const f16x4*)(cT_child +
            (cb0 + l15) * rows_c + csr + quad * 4);
        f16x2 cpack;
        #pragma unroll
        for (int pr = 0; pr < 2; ++pr) {
            float f0 = sigf(af[2 * pr]     + bfv);
            float f1 = sigf(af[2 * pr + 1] + bfv);
            float fc = f0 * (float)cc[2 * pr] + f1 * (float)cc[2 * pr + 1];
            float i_ = au[0][2 * pr] + au[0][2 * pr + 1] + bi;
            float o_ = au[1][2 * pr] + au[1][2 * pr + 1] + bo;
            float u_ = au[2][2 * pr] + au[2][2 * pr + 1] + bu;
            float c  = sigf(i_) * tanh_fast(u_) + fc;
            float h  = sigf(o_) * tanh_fast(c);
            cpack[pr] = (f16)c;
            ldsh[w][(sh * 8 + quad * 2 + pr) * LDSH_S + l15] = (f16)h;
        }
        *(f16x2*)(cT_parent + (cb0 + l15) * rows_p + pw + sh * 8 + quad * 2) = cpack;
    }

    {
        int prow = lane >> 2, cpos = (lane & 3) * 4;
        int p = pw + prow;
        int b = p >> l, tt = p & maskp;
        int node = b * M_NODES + (1 << l) - 1 + tt;
        f16x4 v = *(const f16x4*)(&ldsh[w][prow * LDSH_S + cpos]);
        *(f16x4*)(h16 + node * HDIM + cb0 + cpos) = v;
    }
}

// ---------------------------------------------------------------------------
// TAIL levels (l=4..0) fused into ONE kernel: 32 blocks, block b = tree b.
// R12 failed with absmax 2.6e-3: the ping-pong c-buffers REUSED absolute
// addresses read earlier in the same kernel (cA read at l=4, rewritten at
// l=3, reread at l=2) -> per-CU L1 served STALE lines cached by the l=4
// read (write-through stores need not invalidate; see MI355X correctness
// boundaries). Fix: DISJOINT per-level c sub-buffers in a fresh ctail
// region -- every address is written before it is ever read, so the read
// must miss to L2 (h16 already has this property: level-l nodes are first
// touched by the drain store). Arithmetic unchanged (proven mapping).
// ---------------------------------------------------------------------------
__global__ __launch_bounds__(512) void fused_tail_kernel(
    const f16* __restrict__ Uiou16, const f16* __restrict__ Uf16,
    const float* __restrict__ b_iou, const float* __restrict__ b_f,
    f16* __restrict__ h16, const f16* __restrict__ cT_in,
    f16* __restrict__ ctail)
{
    __shared__ f16 ldsh[8][16 * LDSH_S];

    const int b    = blockIdx.x;               // tree 0..31
    const int tid  = threadIdx.x;
    const int lane = tid & 63;
    const int w    = tid >> 6;                 // 0..7
    const int quad = lane >> 4;
    const int l15  = lane & 15;
    const int qk   = quad * 8;

    // Disjoint per-level parent-c buffers inside ctail (f16 offsets):
    // l=4 at 0 (256x512), l=3 at 131072 (256x256), l=2 at 196608 (256x128),
    // l=1 at 229376 (256x64), l=0 at 245760 (256x32).
    const int coff[5] = {245760, 229376, 196608, 131072, 0};

    for (int l = 4; l >= 0; --l) {
        const int rows_t  = 1 << l;            // parents per tree
        const int crows_t = rows_t * 2;        // children per tree
        const int rows_p  = B_TREES << l;      // total parent level rows
        const int rows_c  = rows_p * 2;        // total child level rows
        const int lc = l + 1;
        const int maskc = (1 << lc) - 1;
        const int maskp = (1 << l) - 1;

        const f16* cread = (l == 4) ? cT_in : (ctail + coff[l + 1]);
        f16*       cwrit = ctail + coff[l];

        #pragma unroll
        for (int pass = 0; pass < 2; ++pass) {
            const int cg  = w + pass * 8;
            const int cb0 = cg * 16;

            const float bi  = b_iou[cb0 + l15];
            const float bo  = b_iou[256 + cb0 + l15];
            const float bu  = b_iou[512 + cb0 + l15];
            const float bfv = b_f[cb0 + l15];

            // children (local rows clamped; clamped lanes feed masked parents)
            int cl0l = l15;      if (cl0l >= crows_t) cl0l = crows_t - 1;
            int cl1l = 16 + l15; if (cl1l >= crows_t) cl1l = crows_t - 1;
            const int cg0 = b * crows_t + cl0l;   // global child level-row
            const int cg1 = b * crows_t + cl1l;
            const int childBase0 = ((cg0 >> lc) * M_NODES + maskc + (cg0 & maskc)) * HDIM;
            const int childBase1 = ((cg1 >> lc) * M_NODES + maskc + (cg1 & maskc)) * HDIM;

            f32x4 accf0 = {}, accf1 = {};
            f32x4 au0[3] = {}, au1[3] = {};
            #pragma unroll
            for (int ks = 0; ks < 8; ++ks) {
                const int k0 = ks * 32 + qk;
                f16x8 a0 = *(const f16x8*)(h16 + childBase0 + k0);
                f16x8 a1 = *(const f16x8*)(h16 + childBase1 + k0);
                // weights direct from global: same fragment the staged path used
                f16x8 wfF = *(const f16x8*)(Uf16 + (cb0 + l15) * HDIM + k0);
                accf0 = __builtin_amdgcn_mfma_f32_16x16x32_f16(a0, wfF, accf0, 0, 0, 0);
                accf1 = __builtin_amdgcn_mfma_f32_16x16x32_f16(a1, wfF, accf1, 0, 0, 0);
                #pragma unroll
                for (int m = 0; m < 3; ++m) {
                    f16x8 wm = *(const f16x8*)(Uiou16 + (m * 256 + cb0 + l15) * HDIM + k0);
                    au0[m] = __builtin_amdgcn_mfma_f32_16x16x32_f16(a0, wm, au0[m], 0, 0, 0);
                    au1[m] = __builtin_amdgcn_mfma_f32_16x16x32_f16(a1, wm, au1[m], 0, 0, 0);
                }
            }

            // Epilogue (guarded, scalar c I/O): parent local j = sh*8+quad*2+pr;
            // child local rows 2j, 2j+1 < crows_t whenever j < rows_t.
            #pragma unroll
            for (int sh = 0; sh < 2; ++sh) {
                const f32x4& af = sh ? accf1 : accf0;
                const f32x4* au = sh ? au1 : au0;
                #pragma unroll
                for (int pr = 0; pr < 2; ++pr) {
                    const int j = sh * 8 + quad * 2 + pr;  // local parent
                    if (j < rows_t) {
                        f16 c0 = cread[(cb0 + l15) * rows_c + b * crows_t + 2 * j];
                        f16 c1 = cread[(cb0 + l15) * rows_c + b * crows_t + 2 * j + 1];
                        float f0 = sigf(af[2 * pr]     + bfv);
                        float f1 = sigf(af[2 * pr + 1] + bfv);
                        float fc = f0 * (float)c0 + f1 * (float)c1;
                        float i_ = au[0][2 * pr] + au[0][2 * pr + 1] + bi;
                        float o_ = au[1][2 * pr] + au[1][2 * pr + 1] + bo;
                        float u_ = au[2][2 * pr] + au[2][2 * pr + 1] + bu;
                        float c  = sigf(i_) * tanh_fast(u_) + fc;
                        float h  = sigf(o_) * tanh_fast(c);
                        cwrit[(cb0 + l15) * rows_p + b * rows_t + j] = (f16)c;
                        ldsh[w][j * LDSH_S + l15] = (f16)h;
                    }
                }
            }

            // Wave-local guarded drain of up to 16 parents x 16 cols
            {
                int prow = lane >> 2, cpos = (lane & 3) * 4;
                if (prow < rows_t) {
                    int gp = b * rows_t + prow;            // global parent row
                    int node = (gp >> l) * M_NODES + (1 << l) - 1 + (gp & maskp);
                    f16x4 v = *(const f16x4*)(&ldsh[w][prow * LDSH_S + cpos]);
                    *(f16x4*)(h16 + node * HDIM + cb0 + cpos) = v;
                }
            }
        } // pass

        __syncthreads();                        // h16/cwrit stores drained
    } // level
}

// ---------------------------------------------------------------------------
// Output: internal nodes only (leaves handled by out_v gather). Grid 256.
// ---------------------------------------------------------------------------
__global__ __launch_bounds__(256) void out_kernel(
    const f16* __restrict__ h16, const f16* __restrict__ Wout16,
    const float* __restrict__ bout, float* __restrict__ out)
{
    const int lane = threadIdx.x & 63;
    const int w    = threadIdx.x >> 6;
    const int quad = lane >> 4;
    const int l15  = lane & 15;
    const int qk   = quad * 8;

    f16x8 wfk[2][8];
    #pragma unroll
    for (int cf = 0; cf < 2; ++cf)
        #pragma unroll
        for (int ks = 0; ks < 8; ++ks)
            wfk[cf][ks] = *(const f16x8*)(Wout16 +
                (cf * 16 + l15) * HDIM + ks * 32 + qk);
    float bo[2];
    #pragma unroll
    for (int cf = 0; cf < 2; ++cf) {
        int col = cf * 16 + l15;
        bo[cf] = bout[col < NCLS ? col : 0];
    }

    const int tile0 = blockIdx.x * 16;             // 4096 tiles total

    for (int rt = w; rt < 16; rt += 4) {
        const int tt = tile0 + rt;
        const int rw = (tt >> 7) * M_NODES + (tt & 127) * 16;  // tree*4095 + idx
        f32x4 acc[2] = {};
        #pragma unroll
        for (int ks = 0; ks < 8; ++ks) {
            f16x8 a = *(const f16x8*)(h16 + (rw + l15) * HDIM + ks * 32 + qk);
            #pragma unroll
            for (int cf = 0; cf < 2; ++cf)
                acc[cf] = __builtin_amdgcn_mfma_f32_16x16x32_f16(
                    a, wfk[cf][ks], acc[cf], 0, 0, 0);
        }
        #pragma unroll
        for (int cf = 0; cf < 2; ++cf) {
            const int col = cf * 16 + l15;
            if (col < NCLS) {
                #pragma unroll
                for (int r = 0; r < 4; ++r)
                    out[(rw + quad * 4 + r) * NCLS + col] = acc[cf][r] + bo[cf];
            }
        }
    }
}

// ---------------------------------------------------------------------------
extern "C" void kernel_launch(void* const* d_in, const int* in_sizes, int n_in,
                              void* d_out, int out_size, void* d_ws, size_t ws_size,
                              hipStream_t stream)
{
    const int*   x     = (const int*)d_in[0];
    // d_in[1] = x_mask: leaf structure is static — folded into indexing.
    const float* Emb   = (const float*)d_in[2];
    const float* W_iou = (const float*)d_in[3];
    const float* b_iou = (const float*)d_in[4];
    const float* U_iou = (const float*)d_in[5];
    const float* U_f   = (const float*)d_in[6];
    const float* b_f   = (const float*)d_in[7];
    const float* W_out = (const float*)d_in[8];
    const float* b_out = (const float*)d_in[9];
    float* out = (float*)d_out;

    char* ws = (char*)d_ws;
    size_t off = 0;
    auto take = [&](size_t bytes) -> char* {
        char* p = ws + off; off += (bytes + 255) & ~(size_t)255; return p;
    };
    f16* h16    = (f16*)take((size_t)N_NODES * HDIM * 2);
    f16* cA     = (f16*)take((size_t)HDIM * LEAFROWS * 2);        // [256][65536]
    f16* cB     = (f16*)take((size_t)HDIM * (LEAFROWS / 2) * 2);  // [256][32768]
    f16* Emb16  = (f16*)take((size_t)VOCAB * HDIM * 2);
    f16* Wiou16 = (f16*)take((size_t)768 * HDIM * 2);
    f16* Uiou16 = (f16*)take((size_t)768 * HDIM * 2);
    f16* Uf16   = (f16*)take((size_t)HDIM * HDIM * 2);
    f16* Wout16 = (f16*)take((size_t)32 * HDIM * 2);
    f16* cv     = (f16*)take((size_t)VOCAB * HDIM * 2);
    float* outv = (float*)take((size_t)VOCAB * NCLS * 4);
    f16* ctail  = (f16*)take((size_t)256 * 1024 * 2);             // tail c levels
    // hv aliased over cB: hv is dead before level-10 (first writer of cB).
    f16* hv     = cB;   // 16.38 MB <= 16.78 MB

    cvt_kernel<<<VOCAB * HDIM / 4 / 256, 256, 0, stream>>>(
        (const float4*)Emb, (const float4*)W_iou, (const float4*)U_iou,
        (const float4*)U_f, (const float4*)W_out,
        (f16x4*)Emb16, (f16x4*)Wiou16, (f16x4*)Uiou16, (f16x4*)Uf16,
        (f16x4*)Wout16);

    // Per-id leaf state tables (32000 rows); XCD-swizzled 1D grid
    vocab_kernel<<<8 * 13 * 16, 256, 0, stream>>>(
        Emb16, Wiou16, b_iou, hv, cv);

    // Per-id output head
    vocab_out_kernel<<<dim3(VOCAB / 16 / 16), 256, 0, stream>>>(
        hv, Wout16, b_out, outv);

    // Leaves: pure gather/scatter of precomputed state
    leaf_scatter_kernel<<<dim3(LEAFROWS / 64), 256, 0, stream>>>(
        x, hv, cv, outv, h16, cA, out);

    // Levels 10..5: ping-pong transposed c buffers.
    // l >= 8: 512 persistent blocks (R8-exact). l = 7,6,5: plain grid.
    f16* cin  = cA;
    f16* cout_ = cB;
    for (int l = 10; l >= 5; --l) {
        int rows_p = B_TREES << l;
        int nstripes = (rows_p + 127) / 128;
        if (l >= 8) {
            fused_level_looped<<<512, 512, 0, stream>>>(
                Uiou16, Uf16, b_iou, b_f, h16, cin, cout_, l, rows_p, nstripes);
        } else {
            fused_level_small<<<nstripes * 16, 512, 0, stream>>>(
                Uiou16, Uf16, b_iou, b_f, h16, cin, cout_, l, rows_p);
        }
        f16* t = cin; cin = cout_; cout_ = t;
    }

    // Levels 4..0 fused: one block per tree, disjoint per-level c buffers.
    // After the l=5 swap, cin holds level-5 c (the tail's first child input).
    fused_tail_kernel<<<32, 512, 0, stream>>>(
        Uiou16, Uf16, b_iou, b_f, h16, cin, ctail);

    // Output head for internal nodes
    out_kernel<<<dim3(32 * 128 / 16), 256, 0, stream>>>(
        h16, Wout16, b_out, out);
}

// Round 14
// 394.960 us; speedup vs baseline: 1.2239x; 1.2239x over previous
//
#include <hip/hip_runtime.h>

// Problem constants (from reference)
#define B_TREES 32
#define DEPTH   12
#define M_NODES 4095                  // 2^12 - 1
#define N_NODES (B_TREES * M_NODES)   // 131040
#define HDIM    256
#define VOCAB   32000
#define NCLS    20
#define LEAFROWS 65536                // 32 * 2048 leaves
#define LDSH_S 20                     // padded stride of 16x16 h transpose tile

typedef _Float16 f16;
typedef _Float16 f16x8 __attribute__((ext_vector_type(8)));
typedef _Float16 f16x4 __attribute__((ext_vector_type(4)));
typedef _Float16 f16x2 __attribute__((ext_vector_type(2)));
typedef float    f32x4 __attribute__((ext_vector_type(4)));

__device__ __forceinline__ float sigf(float x)      { return 1.0f / (1.0f + __expf(-x)); }
__device__ __forceinline__ float tanh_fast(float x) { return 1.0f - 2.0f / (1.0f + __expf(2.0f * x)); }

// ---------------------------------------------------------------------------
// Init: convert Emb + weights to fp16. W_out padded to 32 rows (zeros).
// ---------------------------------------------------------------------------
__global__ __launch_bounds__(256) void cvt_kernel(
    const float4* __restrict__ Emb,  const float4* __restrict__ Wiou,
    const float4* __restrict__ Uiou, const float4* __restrict__ Uf,
    const float4* __restrict__ Wout,
    f16x4* __restrict__ Emb16,  f16x4* __restrict__ Wiou16,
    f16x4* __restrict__ Uiou16, f16x4* __restrict__ Uf16,
    f16x4* __restrict__ Wout16)
{
    int i = blockIdx.x * 256 + threadIdx.x;   // in units of 4 floats
    if (i < VOCAB * HDIM / 4) {
        float4 v = Emb[i];
        f16x4 r; r[0] = (f16)v.x; r[1] = (f16)v.y; r[2] = (f16)v.z; r[3] = (f16)v.w;
        Emb16[i] = r;
    }
    if (i < 768 * HDIM / 4) {
        float4 v = Wiou[i];
        f16x4 r; r[0] = (f16)v.x; r[1] = (f16)v.y; r[2] = (f16)v.z; r[3] = (f16)v.w;
        Wiou16[i] = r;
        float4 u = Uiou[i];
        f16x4 s; s[0] = (f16)u.x; s[1] = (f16)u.y; s[2] = (f16)u.z; s[3] = (f16)u.w;
        Uiou16[i] = s;
    }
    if (i < HDIM * HDIM / 4) {
        float4 v = Uf[i];
        f16x4 r; r[0] = (f16)v.x; r[1] = (f16)v.y; r[2] = (f16)v.z; r[3] = (f16)v.w;
        Uf16[i] = r;
    }
    if (i < 32 * HDIM / 4) {                  // 32 padded rows of W_out
        int row = i >> 6;
        f16x4 r = {};
        if (row < NCLS) {
            float4 v = Wout[i];
            r[0] = (f16)v.x; r[1] = (f16)v.y; r[2] = (f16)v.z; r[3] = (f16)v.w;
        }
        Wout16[i] = r;
    }
}

// ---------------------------------------------------------------------------
// Vocab kernel: leaf h,c are pure functions of token id (h_sum = fc_sum = 0),
// so compute them ONCE per vocab entry: hv[id][256], cv[id][256] (f16).
// Sequential-row GEMM (32000 rows, no gather). 1D grid, XCD-aware: blocks
// round-robin across 8 XCD L2s by id%8; each XCD owns a contiguous stripe
// range with all 16 col-groups (Emb stripe fetched into exactly ONE XCD L2,
// re-read 15x from it). Grid 1664 = 8 xcd * 13 sl * 16 cg.
// ---------------------------------------------------------------------------
#define VTPW 5
__global__ __launch_bounds__(256) void vocab_kernel(
    const f16* __restrict__ Emb16, const f16* __restrict__ Wiou16,
    const float* __restrict__ b_iou,
    f16* __restrict__ hv, f16* __restrict__ cv)
{
    __shared__ f16 wlds[1536 * 8];             // 24 KB: [mat][ks][quad][col] 16B frags
    __shared__ f16 ldshH[4][16 * LDSH_S];
    __shared__ f16 ldshC[4][16 * LDSH_S];

    const int id     = blockIdx.x;
    const int xcd    = id & 7;
    const int slot   = id >> 3;
    const int cg     = slot & 15;
    const int stripe = xcd * 13 + (slot >> 4);
    if (stripe >= 100) return;                 // padded tail (uniform per block)

    const int tid  = threadIdx.x;
    const int lane = tid & 63;
    const int w    = tid >> 6;
    const int quad = lane >> 4;
    const int l15  = lane & 15;
    const int qk   = quad * 8;
    const int cb0  = cg * 16;                  // block's 16 cols

    // Stage weights (frag f = mat*512 + ks*64 + quad*16 + col)
    #pragma unroll
    for (int i = 0; i < 6; ++i) {
        int f = i * 256 + tid;
        int mat = f >> 9, r = f & 511, ks = r >> 6, q = (r >> 4) & 3, c = r & 15;
        *(f16x8*)(wlds + f * 8) = *(const f16x8*)(Wiou16 +
            (mat * 256 + cb0 + c) * HDIM + ks * 32 + q * 8);
    }
    __syncthreads();

    const float bi = b_iou[cb0 + l15];
    const float bo = b_iou[256 + cb0 + l15];
    const float bu = b_iou[512 + cb0 + l15];

    const int row0 = (stripe * 4 + w) * (VTPW * 16);  // wave's 80 rows

    // Prefetch tile 0 (sequential rows, no indirection)
    f16x8 a[8];
    #pragma unroll
    for (int ks = 0; ks < 8; ++ks)
        a[ks] = *(const f16x8*)(Emb16 + (row0 + l15) * HDIM + ks * 32 + qk);

    for (int rt = 0; rt < VTPW; ++rt) {
        const int rw = row0 + rt * 16;
        f16x8 ac[8];
        #pragma unroll
        for (int ks = 0; ks < 8; ++ks) ac[ks] = a[ks];

        if (rt + 1 < VTPW) {                   // prefetch next tile
            #pragma unroll
            for (int ks = 0; ks < 8; ++ks)
                a[ks] = *(const f16x8*)(Emb16 + (rw + 16 + l15) * HDIM + ks * 32 + qk);
        }

        f32x4 acc[3] = {};
        #pragma unroll
        for (int ks = 0; ks < 8; ++ks) {
            #pragma unroll
            for (int mat = 0; mat < 3; ++mat) {
                f16x8 wf = *(const f16x8*)(wlds +
                    ((mat * 8 + ks) * 64 + quad * 16 + l15) * 8);
                acc[mat] = __builtin_amdgcn_mfma_f32_16x16x32_f16(
                    ac[ks], wf, acc[mat], 0, 0, 0);
            }
        }

        // Epilogue: activations, transpose both h and c tiles via LDS
        #pragma unroll
        for (int r = 0; r < 4; ++r) {
            float i_ = acc[0][r] + bi;
            float o_ = acc[1][r] + bo;
            float u_ = acc[2][r] + bu;
            float c  = sigf(i_) * tanh_fast(u_);
            float h  = sigf(o_) * tanh_fast(c);
            ldshH[w][(quad * 4 + r) * LDSH_S + l15] = (f16)h;
            ldshC[w][(quad * 4 + r) * LDSH_S + l15] = (f16)c;
        }

        // Wave-local drain (row-major hv / cv, 8B stores)
        {
            int row_l = lane >> 2, cpos = (lane & 3) * 4;
            f16x4 vh = *(const f16x4*)(&ldshH[w][row_l * LDSH_S + cpos]);
            *(f16x4*)(hv + (rw + row_l) * HDIM + cb0 + cpos) = vh;
            f16x4 vc = *(const f16x4*)(&ldshC[w][row_l * LDSH_S + cpos]);
            *(f16x4*)(cv + (rw + row_l) * HDIM + cb0 + cpos) = vc;
        }
    }
}

// ---------------------------------------------------------------------------
// Vocab output head: out_v[id] = hv[id] @ W_out^T + b_out (fp32, 20 cols).
// Leaf output rows then become an 80 B gather. Grid 125 (2000 16-row tiles).
// ---------------------------------------------------------------------------
__global__ __launch_bounds__(256) void vocab_out_kernel(
    const f16* __restrict__ hv, const f16* __restrict__ Wout16,
    const float* __restrict__ bout, float* __restrict__ out_v)
{
    const int lane = threadIdx.x & 63;
    const int w    = threadIdx.x >> 6;
    const int quad = lane >> 4;
    const int l15  = lane & 15;
    const int qk   = quad * 8;

    f16x8 wfk[2][8];
    #pragma unroll
    for (int cf = 0; cf < 2; ++cf)
        #pragma unroll
        for (int ks = 0; ks < 8; ++ks)
            wfk[cf][ks] = *(const f16x8*)(Wout16 +
                (cf * 16 + l15) * HDIM + ks * 32 + qk);
    float bo[2];
    #pragma unroll
    for (int cf = 0; cf < 2; ++cf) {
        int col = cf * 16 + l15;
        bo[cf] = bout[col < NCLS ? col : 0];
    }

    const int tile0 = blockIdx.x * 16;         // 2000 tiles total, grid 125

    for (int rt = w; rt < 16; rt += 4) {
        const int rw = (tile0 + rt) * 16;
        f32x4 acc[2] = {};
        #pragma unroll
        for (int ks = 0; ks < 8; ++ks) {
            f16x8 a = *(const f16x8*)(hv + (rw + l15) * HDIM + ks * 32 + qk);
            #pragma unroll
            for (int cf = 0; cf < 2; ++cf)
                acc[cf] = __builtin_amdgcn_mfma_f32_16x16x32_f16(
                    a, wfk[cf][ks], acc[cf], 0, 0, 0);
        }
        #pragma unroll
        for (int cf = 0; cf < 2; ++cf) {
            const int col = cf * 16 + l15;
            if (col < NCLS) {
                #pragma unroll
                for (int r = 0; r < 4; ++r)
                    out_v[(rw + quad * 4 + r) * NCLS + col] = acc[cf][r] + bo[cf];
            }
        }
    }
}

// ---------------------------------------------------------------------------
// Leaf scatter: per leaf row, gather hv[id] -> h16[node] (coalesced copy),
// cv[id] -> LDS -> transposed cT[col][row], out_v[id] -> out[node] rows.
// 64 leaves per block, grid 1024.
// ---------------------------------------------------------------------------
__global__ __launch_bounds__(256) void leaf_scatter_kernel(
    const int* __restrict__ x, const f16* __restrict__ hv,
    const f16* __restrict__ cv, const float* __restrict__ out_v,
    f16* __restrict__ h16, f16* __restrict__ cT, float* __restrict__ out)
{
    __shared__ int ids[64];
    __shared__ f16 ldsc[64][HDIM + 8];         // +16B pad: 2-way (free) col reads

    const int tid = threadIdx.x;
    const int R0  = blockIdx.x * 64;           // block's 64 leaf rows

    if (tid < 64) {
        int r = R0 + tid;
        int node = (r >> 11) * M_NODES + 2047 + (r & 2047);
        ids[tid] = x[node];
    }
    __syncthreads();

    const int r    = tid >> 2;                 // 0..63
    const int p    = tid & 3;                  // 0..3  (128 B segment)
    const int id   = ids[r];
    const int gr   = R0 + r;
    const int node = (gr >> 11) * M_NODES + 2047 + (gr & 2047);

    // h: gather row -> coalesced row-major write
    #pragma unroll
    for (int j = 0; j < 8; ++j) {
        f16x8 v = *(const f16x8*)(hv + id * HDIM + p * 64 + j * 8);
        *(f16x8*)(h16 + node * HDIM + p * 64 + j * 8) = v;
    }
    // c: gather row -> LDS (row-major stage)
    #pragma unroll
    for (int j = 0; j < 8; ++j) {
        f16x8 v = *(const f16x8*)(cv + id * HDIM + p * 64 + j * 8);
        *(f16x8*)(&ldsc[r][p * 64 + j * 8]) = v;
    }
    // out head: 20 floats per leaf, 5 per thread
    #pragma unroll
    for (int j = 0; j < 5; ++j)
        out[node * NCLS + p * 5 + j] = out_v[id * NCLS + p * 5 + j];

    __syncthreads();

    // transpose drain: thread owns col tid, writes 128 B contiguous per col
    {
        const int c = tid;
        f16 tmp[64];
        #pragma unroll
        for (int rr = 0; rr < 64; ++rr) tmp[rr] = ldsc[rr][c];
        #pragma unroll
        for (int j = 0; j < 8; ++j)
            *(f16x8*)(cT + c * LEAFROWS + R0 + j * 8) = *(const f16x8*)(&tmp[j * 8]);
    }
}

// ---------------------------------------------------------------------------
// Fused level kernel (R8-exact): persistent stripe loop at big levels.
// dur at l=10 tracks BLOCK COUNT (256 blk=86µs, 2048=90, 4096=101), not HBM
// traffic (35 vs 148 MB: both 101). Short-lived blocks pay weight-staging
// latency + dispatch per 128 parents, and 1-tile blocks give the scheduler
// no next iteration to overlap loads with.
// l>=8: grid = 512 persistent blocks (8 xcd * 16 cg * 4 slots). Block stages
// its cg's 32 KB weight tile ONCE, then loops spx/4 stripes; loop iterations
// are independent so iteration i+1's 16 A-loads overlap iteration i's
// epilogue. XCD-bijective stripe partition (FETCH ~unique, proven R7).
// Small levels (l<=7): plain grid nstripes*16, single tile per wave.
// R9/R10 lesson: explicit register prefetch trades occupancy 1:1 (spill at
// 8w/EU, occupancy loss at 4w/EU) -- net null or worse. This is the floor.
// ---------------------------------------------------------------------------
__global__ __launch_bounds__(512) void fused_level_kernel(
    const f16* __restrict__ Uiou16, const f16* __restrict__ Uf16,
    const float* __restrict__ b_iou, const float* __restrict__ b_f,
    f16* __restrict__ h16, const f16* __restrict__ cT_child,
    f16* __restrict__ cT_parent, int l, int rows_p, int nstripes, int looped)
{
    __shared__ f16 wlds[2048 * 8];             // 32 KB: mat0=Uf, mat1..3=Uiou
    __shared__ f16 ldsh[8][16 * LDSH_S];

    const int id = blockIdx.x;
    int cg, sbase, sfirst, scount, sstep;
    if (looped) {                              // grid 512 = 8 xcd * 16 cg * 4
        cg     = (id >> 3) & 15;
        int spx = nstripes >> 3;               // stripes per xcd (nstripes%8==0)
        sbase  = (id & 7) * spx;
        sfirst = id >> 7;                      // slot 0..3
        scount = spx;
        sstep  = 4;
    } else {
        cg     = id & 15;
        sbase  = id >> 4;
        sfirst = 0;
        scount = 1;
        sstep  = 1;
    }

    const int tid  = threadIdx.x;
    const int lane = tid & 63;
    const int w    = tid >> 6;                 // 0..7
    const int quad = lane >> 4;
    const int l15  = lane & 15;
    const int qk   = quad * 8;
    const int cb0  = cg * 16;

    // Stage weights once per block (2048 frags, 512 threads -> 4 iters)
    #pragma unroll
    for (int i = 0; i < 4; ++i) {
        int f = i * 512 + tid;
        int mat = f >> 9, r = f & 511, ks = r >> 6, q = (r >> 4) & 3, c = r & 15;
        const f16* src = (mat == 0)
            ? (Uf16 + (cb0 + c) * HDIM + ks * 32 + q * 8)
            : (Uiou16 + ((mat - 1) * 256 + cb0 + c) * HDIM + ks * 32 + q * 8);
        *(f16x8*)(wlds + f * 8) = *(const f16x8*)src;
    }
    __syncthreads();

    const float bi  = b_iou[cb0 + l15];
    const float bo  = b_iou[256 + cb0 + l15];
    const float bu  = b_iou[512 + cb0 + l15];
    const float bfv = b_f[cb0 + l15];
    const int lc = l + 1;
    const int maskc = (1 << lc) - 1;
    const int maskp = (1 << l) - 1;
    const int rows_c = rows_p * 2;

    for (int s = sfirst; s < scount; s += sstep) {
        const int stripe = sbase + s;
        const int pw = stripe * 128 + w * 16;  // wave's 16-parent tile
        if (pw >= rows_p) continue;            // tail waves at tiny levels
        const int cw = 2 * pw;

        int childBase0, childBase1;
        {
            int cl0 = cw + l15;
            childBase0 = ((cl0 >> lc) * M_NODES + maskc + (cl0 & maskc)) * HDIM;
            int cl1 = cw + 16 + l15;
            childBase1 = ((cl1 >> lc) * M_NODES + maskc + (cl1 & maskc)) * HDIM;
        }

        f32x4 accf0 = {}, accf1 = {};
        f32x4 au0[3] = {}, au1[3] = {};
        #pragma unroll
        for (int ks = 0; ks < 8; ++ks) {
            const int k0 = ks * 32 + qk;
            f16x8 a0 = *(const f16x8*)(h16 + childBase0 + k0);
            f16x8 a1 = *(const f16x8*)(h16 + childBase1 + k0);
            f16x8 wfF = *(const f16x8*)(wlds + (ks * 64 + quad * 16 + l15) * 8);
            accf0 = __builtin_amdgcn_mfma_f32_16x16x32_f16(a0, wfF, accf0, 0, 0, 0);
            accf1 = __builtin_amdgcn_mfma_f32_16x16x32_f16(a1, wfF, accf1, 0, 0, 0);
            #pragma unroll
            for (int m = 0; m < 3; ++m) {
                f16x8 wm = *(const f16x8*)(wlds +
                    (((m + 1) * 8 + ks) * 64 + quad * 16 + l15) * 8);
                au0[m] = __builtin_amdgcn_mfma_f32_16x16x32_f16(a0, wm, au0[m], 0, 0, 0);
                au1[m] = __builtin_amdgcn_mfma_f32_16x16x32_f16(a1, wm, au1[m], 0, 0, 0);
            }
        }

        // Epilogue: two child sets -> parents pw..pw+7 and pw+8..pw+15
        #pragma unroll
        for (int sh = 0; sh < 2; ++sh) {
            const f32x4& af = sh ? accf1 : accf0;
            const f32x4* au = sh ? au1 : au0;
            const int csr = cw + sh * 16;         // child rows of this set
            f16x4 cc = *(const f16x4*)(cT_child +
                (cb0 + l15) * rows_c + csr + quad * 4);
            f16x2 cpack;
            #pragma unroll
            for (int pr = 0; pr < 2; ++pr) {
                float f0 = sigf(af[2 * pr]     + bfv);
                float f1 = sigf(af[2 * pr + 1] + bfv);
                float fc = f0 * (float)cc[2 * pr] + f1 * (float)cc[2 * pr + 1];
                float i_ = au[0][2 * pr] + au[0][2 * pr + 1] + bi;
                float o_ = au[1][2 * pr] + au[1][2 * pr + 1] + bo;
                float u_ = au[2][2 * pr] + au[2][2 * pr + 1] + bu;
                float c  = sigf(i_) * tanh_fast(u_) + fc;
                float h  = sigf(o_) * tanh_fast(c);
                cpack[pr] = (f16)c;
                ldsh[w][(sh * 8 + quad * 2 + pr) * LDSH_S + l15] = (f16)h;
            }
            *(f16x2*)(cT_parent + (cb0 + l15) * rows_p + pw + sh * 8 + quad * 2) = cpack;
        }

        // Wave-local drain of 16-parent x 16-col h tile (8B stores)
        {
            int prow = lane >> 2, cpos = (lane & 3) * 4;
            int p = pw + prow;
            int b = p >> l, tt = p & maskp;
            int node = b * M_NODES + (1 << l) - 1 + tt;
            f16x4 v = *(const f16x4*)(&ldsh[w][prow * LDSH_S + cpos]);
            *(f16x4*)(h16 + node * HDIM + cb0 + cpos) = v;
        }
    }
}

// ---------------------------------------------------------------------------
// Output: internal nodes only (leaves handled by out_v gather). 32 trees x
// 128 tiles of 16 rows = 4096 tiles (tile 127's last row is leaf idx 2047:
// harmless duplicate, h16 is valid there). Grid 256.
// ---------------------------------------------------------------------------
__global__ __launch_bounds__(256) void out_kernel(
    const f16* __restrict__ h16, const f16* __restrict__ Wout16,
    const float* __restrict__ bout, float* __restrict__ out)
{
    const int lane = threadIdx.x & 63;
    const int w    = threadIdx.x >> 6;
    const int quad = lane >> 4;
    const int l15  = lane & 15;
    const int qk   = quad * 8;

    f16x8 wfk[2][8];
    #pragma unroll
    for (int cf = 0; cf < 2; ++cf)
        #pragma unroll
        for (int ks = 0; ks < 8; ++ks)
            wfk[cf][ks] = *(const f16x8*)(Wout16 +
                (cf * 16 + l15) * HDIM + ks * 32 + qk);
    float bo[2];
    #pragma unroll
    for (int cf = 0; cf < 2; ++cf) {
        int col = cf * 16 + l15;
        bo[cf] = bout[col < NCLS ? col : 0];
    }

    const int tile0 = blockIdx.x * 16;             // 4096 tiles total

    for (int rt = w; rt < 16; rt += 4) {
        const int tt = tile0 + rt;
        const int rw = (tt >> 7) * M_NODES + (tt & 127) * 16;  // tree*4095 + idx
        f32x4 acc[2] = {};
        #pragma unroll
        for (int ks = 0; ks < 8; ++ks) {
            f16x8 a = *(const f16x8*)(h16 + (rw + l15) * HDIM + ks * 32 + qk);
            #pragma unroll
            for (int cf = 0; cf < 2; ++cf)
                acc[cf] = __builtin_amdgcn_mfma_f32_16x16x32_f16(
                    a, wfk[cf][ks], acc[cf], 0, 0, 0);
        }
        #pragma unroll
        for (int cf = 0; cf < 2; ++cf) {
            const int col = cf * 16 + l15;
            if (col < NCLS) {
                #pragma unroll
                for (int r = 0; r < 4; ++r)
                    out[(rw + quad * 4 + r) * NCLS + col] = acc[cf][r] + bo[cf];
            }
        }
    }
}

// ---------------------------------------------------------------------------
extern "C" void kernel_launch(void* const* d_in, const int* in_sizes, int n_in,
                              void* d_out, int out_size, void* d_ws, size_t ws_size,
                              hipStream_t stream)
{
    const int*   x     = (const int*)d_in[0];
    // d_in[1] = x_mask: leaf structure is static — folded into indexing.
    const float* Emb   = (const float*)d_in[2];
    const float* W_iou = (const float*)d_in[3];
    const float* b_iou = (const float*)d_in[4];
    const float* U_iou = (const float*)d_in[5];
    const float* U_f   = (const float*)d_in[6];
    const float* b_f   = (const float*)d_in[7];
    const float* W_out = (const float*)d_in[8];
    const float* b_out = (const float*)d_in[9];
    float* out = (float*)d_out;

    char* ws = (char*)d_ws;
    size_t off = 0;
    auto take = [&](size_t bytes) -> char* {
        char* p = ws + off; off += (bytes + 255) & ~(size_t)255; return p;
    };
    f16* h16    = (f16*)take((size_t)N_NODES * HDIM * 2);
    f16* cA     = (f16*)take((size_t)HDIM * LEAFROWS * 2);        // [256][65536]
    f16* cB     = (f16*)take((size_t)HDIM * (LEAFROWS / 2) * 2);  // [256][32768]
    f16* Emb16  = (f16*)take((size_t)VOCAB * HDIM * 2);
    f16* Wiou16 = (f16*)take((size_t)768 * HDIM * 2);
    f16* Uiou16 = (f16*)take((size_t)768 * HDIM * 2);
    f16* Uf16   = (f16*)take((size_t)HDIM * HDIM * 2);
    f16* Wout16 = (f16*)take((size_t)32 * HDIM * 2);
    f16* cv     = (f16*)take((size_t)VOCAB * HDIM * 2);
    float* outv = (float*)take((size_t)VOCAB * NCLS * 4);
    // hv aliased over cB: hv is dead before level-10 (first writer of cB).
    f16* hv     = cB;   // 16.38 MB <= 16.78 MB

    cvt_kernel<<<VOCAB * HDIM / 4 / 256, 256, 0, stream>>>(
        (const float4*)Emb, (const float4*)W_iou, (const float4*)U_iou,
        (const float4*)U_f, (const float4*)W_out,
        (f16x4*)Emb16, (f16x4*)Wiou16, (f16x4*)Uiou16, (f16x4*)Uf16,
        (f16x4*)Wout16);

    // Per-id leaf state tables (32000 rows); XCD-swizzled 1D grid
    vocab_kernel<<<8 * 13 * 16, 256, 0, stream>>>(
        Emb16, Wiou16, b_iou, hv, cv);

    // Per-id output head
    vocab_out_kernel<<<dim3(VOCAB / 16 / 16), 256, 0, stream>>>(
        hv, Wout16, b_out, outv);

    // Leaves: pure gather/scatter of precomputed state
    leaf_scatter_kernel<<<dim3(LEAFROWS / 64), 256, 0, stream>>>(
        x, hv, cv, outv, h16, cA, out);

    // Levels 10..0, fused fgate+iou, ping-pong transposed c buffers.
    // l >= 8: 512 persistent blocks looping stripes (weights staged once,
    //         cross-iteration load overlap, XCD-bijective stripe ownership).
    // l <= 7: plain grid nstripes*16.
    f16* cin  = cA;
    f16* cout_ = cB;
    for (int l = 10; l >= 0; --l) {
        int rows_p = B_TREES << l;
        int nstripes = (rows_p + 127) / 128;
        int looped = (l >= 8) ? 1 : 0;
        int grid = looped ? 512 : nstripes * 16;
        fused_level_kernel<<<grid, 512, 0, stream>>>(
            Uiou16, Uf16, b_iou, b_f, h16, cin, cout_, l, rows_p, nstripes, looped);
        f16* t = cin; cin = cout_; cout_ = t;
    }

    // Output head for internal nodes
    out_kernel<<<dim3(32 * 128 / 16), 256, 0, stream>>>(
        h16, Wout16, b_out, out);
}